// Round 5
// baseline (1889.511 us; speedup 1.0000x reference)
//
#include <hip/hip_runtime.h>
#include <math.h>

constexpr int CH   = 128;      // CH_IN == CH_LAT == CLASSES
constexpr int WW   = 131072;   // W
constexpr int NB   = 4;        // B
constexpr int NPIX = NB * WW;  // 524288
constexpr int TPB  = 512;

// ws float layout (w1t and w2g contiguous so one LDS copy covers both):
constexpr int OFF_W1T = 0;        // w1t[c][o], 128*128
constexpr int OFF_W2G = 16384;    // w2 grouped [rg][c][j8]: w2g[rg*1024+c*8+j] = w2[(rg*8+j)*128+c]
constexpr int OFF_BNA = 32768;    // BN scale, 128
constexpr int OFF_BNC = 32896;    // BN offset (b1 folded), 128
constexpr int OFF_WM  = 33024;    // w2 row 128 (mask row), 128

__global__ __launch_bounds__(256) void prep_kernel(
    const float* __restrict__ w1, const float* __restrict__ b1,
    const float* __restrict__ gamma, const float* __restrict__ beta,
    const float* __restrict__ mean, const float* __restrict__ var,
    const float* __restrict__ w2,
    float* __restrict__ ws)
{
    const int gid    = blockIdx.x * 256 + threadIdx.x;
    const int stride = gridDim.x * 256;
    for (int i = gid; i < CH * CH; i += stride) {
        const int c = i >> 7, o = i & 127;
        ws[OFF_W1T + c * CH + o] = w1[o * CH + c];
    }
    for (int i = gid; i < 16 * CH * 8; i += stride) {
        const int rg = i >> 10, r = i & 1023, c = r >> 3, j = r & 7;
        ws[OFF_W2G + i] = w2[(rg * 8 + j) * CH + c];
    }
    if (gid < CH) {
        const float s = gamma[gid] / sqrtf(var[gid] + 1e-5f);   // identical math to R1-R4
        ws[OFF_BNA + gid] = s;
        ws[OFF_BNC + gid] = (b1[gid] - mean[gid]) * s + beta[gid];
        ws[OFF_WM  + gid] = w2[CH * CH + gid];
    }
}

// Weights delivered via same-address LDS broadcast (conflict-free), x via 8-deep
// ping-pong prefetch, latent in 128 static VGPRs. All reduction chains keep the
// exact associativity of rounds 1-4.
__global__ __launch_bounds__(TPB, 1) void fused_kernel(
    const float* __restrict__ x,     // (B,128,1,W)
    const float* __restrict__ b2,    // (129)
    const float* __restrict__ cmw,   // (128,128)
    const float* __restrict__ cmb,   // (128)
    const float* __restrict__ ws,
    float* __restrict__ out)         // [0,NPIX): reg-out, [NPIX,2NPIX): mask
{
    __shared__ float lw1[CH * CH];       // 64KB: w1t[c][o]
    __shared__ float lw2[16 * CH * 8];   // 64KB: w2g[rg][c][j]

    const int tid = threadIdx.x;

    // ---- cooperative LDS fill: 32768 floats = 8192 float4, 512 threads ----
    {
        const float4* __restrict__ s1 = (const float4*)(ws + OFF_W1T);
        float4* d1 = (float4*)lw1;
        #pragma unroll
        for (int k = 0; k < 8; ++k) d1[k * TPB + tid] = s1[k * TPB + tid];
        const float4* __restrict__ s2 = (const float4*)(ws + OFF_W2G);
        float4* d2 = (float4*)lw2;
        #pragma unroll
        for (int k = 0; k < 8; ++k) d2[k * TPB + tid] = s2[k * TPB + tid];
    }
    __syncthreads();

    const int p = blockIdx.x * TPB + tid;
    const int b = p >> 17;                    // / W (uniform per block: 131072 % 512 == 0)
    const int w = p & (WW - 1);

    const float* __restrict__ bnA = ws + OFF_BNA;
    const float* __restrict__ bnC = ws + OFF_BNC;
    const float* __restrict__ wm  = ws + OFF_WM;

    // ---- GEMM1: acc[o] = sum_c x[b,c,w] * w1[o][c] (chain order == R1-R4) ----
    float acc[CH];
    #pragma unroll
    for (int o = 0; o < CH; ++o) acc[o] = 0.f;

    const float* xc = x + ((size_t)b * CH) * WW + w;
    float xa[8], xnx[8];
    #pragma unroll
    for (int k = 0; k < 8; ++k) xa[k] = xc[(size_t)k * WW];

    #pragma unroll 1
    for (int cg = 0; cg < CH - 8; cg += 8) {
        // prefetch next 8 channels (cg+8 .. cg+15, max 127: in bounds)
        #pragma unroll
        for (int k = 0; k < 8; ++k) xnx[k] = xc[(size_t)(cg + 8 + k) * WW];
        #pragma unroll
        for (int k = 0; k < 8; ++k) {
            const float xv = xa[k];
            const float4* __restrict__ wr = (const float4*)&lw1[(cg + k) * CH];
            #pragma unroll
            for (int o4 = 0; o4 < 32; ++o4) {
                const float4 w4 = wr[o4];                  // LDS broadcast
                acc[o4*4+0] = fmaf(xv, w4.x, acc[o4*4+0]);
                acc[o4*4+1] = fmaf(xv, w4.y, acc[o4*4+1]);
                acc[o4*4+2] = fmaf(xv, w4.z, acc[o4*4+2]);
                acc[o4*4+3] = fmaf(xv, w4.w, acc[o4*4+3]);
            }
        }
        #pragma unroll
        for (int k = 0; k < 8; ++k) xa[k] = xnx[k];
    }
    // final 8 channels (c = 120..127)
    #pragma unroll
    for (int k = 0; k < 8; ++k) {
        const float xv = xa[k];
        const float4* __restrict__ wr = (const float4*)&lw1[(120 + k) * CH];
        #pragma unroll
        for (int o4 = 0; o4 < 32; ++o4) {
            const float4 w4 = wr[o4];
            acc[o4*4+0] = fmaf(xv, w4.x, acc[o4*4+0]);
            acc[o4*4+1] = fmaf(xv, w4.y, acc[o4*4+1]);
            acc[o4*4+2] = fmaf(xv, w4.z, acc[o4*4+2]);
            acc[o4*4+3] = fmaf(xv, w4.w, acc[o4*4+3]);
        }
    }

    // ---- BN + LeakyReLU (b1 folded), in registers ----
    #pragma unroll
    for (int o = 0; o < CH; ++o) {
        const float v = fmaf(acc[o], bnA[o], bnC[o]);
        acc[o] = (v >= 0.f) ? v : 0.01f * v;
    }

    // ---- GEMM2 rows 0..127: 16 groups of 8, c fully unrolled (static acc[c]) ----
    float best = -3.0e38f;
    int   bidx = 0;
    #pragma unroll 1
    for (int rg = 0; rg < 16; ++rg) {
        float y[8];
        #pragma unroll
        for (int j = 0; j < 8; ++j) y[j] = b2[rg * 8 + j];         // uniform s_load
        const float* __restrict__ wg = &lw2[rg * (CH * 8)];
        #pragma unroll
        for (int c = 0; c < CH; ++c) {
            const float4 wa = *(const float4*)&wg[c * 8];          // LDS broadcast
            const float4 wb = *(const float4*)&wg[c * 8 + 4];
            y[0] = fmaf(acc[c], wa.x, y[0]);
            y[1] = fmaf(acc[c], wa.y, y[1]);
            y[2] = fmaf(acc[c], wa.z, y[2]);
            y[3] = fmaf(acc[c], wa.w, y[3]);
            y[4] = fmaf(acc[c], wb.x, y[4]);
            y[5] = fmaf(acc[c], wb.y, y[5]);
            y[6] = fmaf(acc[c], wb.z, y[6]);
            y[7] = fmaf(acc[c], wb.w, y[7]);
        }
        #pragma unroll
        for (int j = 0; j < 8; ++j) {
            const bool g = y[j] > best;                            // strict >, ascending
            best = g ? y[j] : best;
            bidx = g ? rg * 8 + j : bidx;
        }
    }

    // ---- mask row (w2 row 128): single chain, init b2[128], c ascending ----
    {
        float m = b2[CH];
        #pragma unroll
        for (int c = 0; c < CH; ++c)
            m = fmaf(acc[c], wm[c], m);
        out[NPIX + p] = (m >= 0.f) ? m : 0.01f * m;
    }

    // ---- cm gather (per-lane, L2) + reg dot: 4-way split as in R1-R4 ----
    {
        const float4* __restrict__ cr = (const float4*)(cmw + (size_t)bidx * CH);
        float r0 = 0.f, r1 = 0.f, r2 = 0.f, r3 = 0.f;
        #pragma unroll
        for (int c4 = 0; c4 < 32; ++c4) {
            const float4 v = cr[c4];
            r0 = fmaf(acc[c4*4+0], v.x, r0);
            r1 = fmaf(acc[c4*4+1], v.y, r1);
            r2 = fmaf(acc[c4*4+2], v.z, r2);
            r3 = fmaf(acc[c4*4+3], v.w, r3);
        }
        const float reg = ((r0 + r1) + (r2 + r3)) + cmb[bidx];
        out[p] = ((float)bidx + reg) * (1.0f / 128.0f);
    }
}

extern "C" void kernel_launch(void* const* d_in, const int* in_sizes, int n_in,
                              void* d_out, int out_size, void* d_ws, size_t ws_size,
                              hipStream_t stream) {
    const float* x     = (const float*)d_in[0];
    const float* w1    = (const float*)d_in[1];
    const float* b1    = (const float*)d_in[2];
    const float* gamma = (const float*)d_in[3];
    const float* beta  = (const float*)d_in[4];
    const float* mean  = (const float*)d_in[5];
    const float* var   = (const float*)d_in[6];
    const float* w2    = (const float*)d_in[7];
    const float* b2    = (const float*)d_in[8];
    const float* cmw   = (const float*)d_in[9];
    const float* cmb   = (const float*)d_in[10];
    float* ws  = (float*)d_ws;
    float* out = (float*)d_out;

    hipLaunchKernelGGL(prep_kernel, dim3(64), dim3(256), 0, stream,
                       w1, b1, gamma, beta, mean, var, w2, ws);
    hipLaunchKernelGGL(fused_kernel, dim3(NPIX / TPB), dim3(TPB), 0, stream,
                       x, b2, cmw, cmb, ws, out);
}